// Round 1
// baseline (14843.716 us; speedup 1.0000x reference)
//
#include <hip/hip_runtime.h>
#include <hip/hip_bf16.h>

// MotionFormerBlock on MI355X — Round 1: fp32 correctness-first implementation.
// B=8, H=W=128, DIM=256, HEADS=8 (hd=32), MOTION_DIM=128 (md=16), WS=8 (T=64),
// HIDDEN=1024. 2048 windows; window partner = batch (b+4)%8, same spatial window.
//
// Pipeline: k_ln1 -> k_attn (fused qkv per window) -> k_proj(+res) -> k_motion
//           -> k_fc1 (fused LN2) -> k_conv (dw3x3+gelu) -> k_fc2(+res)
//
// Workspace layout (bytes), peak 512 MiB with aliasing:
//   xnorm f32  [0,          134217728)
//   af    f32  [134217728,  268435456)
//   mfraw f32  [268435456,  335544320)
//   h1    bf16 [0,          268435456)   (after k_proj: xnorm/af dead)
//   h2    bf16 [268435456,  536870912)   (after k_motion: mfraw dead)

#define NTOK 131072        // 8*128*128
#define DIM 256
#define HIDDEN 1024
#define MDIM 128

static __device__ __forceinline__ unsigned short f2bfbits(float f) {
  __hip_bfloat16 h = __float2bfloat16(f);
  return *reinterpret_cast<unsigned short*>(&h);
}
static __device__ __forceinline__ float bfbits2f(unsigned short u) {
  return __uint_as_float(((unsigned)u) << 16);
}

// ---------------- LayerNorm1: one wave per token, float4 ----------------
__global__ __launch_bounds__(256) void k_ln1(const float* __restrict__ x,
    const float* __restrict__ g, const float* __restrict__ b,
    float* __restrict__ o) {
  int lane = threadIdx.x & 63;
  size_t t = (size_t)blockIdx.x * 4 + (threadIdx.x >> 6);
  const float4* xr = (const float4*)(x + t * 256);
  float4 v = xr[lane];
  float s = v.x + v.y + v.z + v.w;
  float ss = v.x*v.x + v.y*v.y + v.z*v.z + v.w*v.w;
  #pragma unroll
  for (int m = 32; m; m >>= 1) { s += __shfl_xor(s, m, 64); ss += __shfl_xor(ss, m, 64); }
  float mean = s * (1.0f/256.0f);
  float var = ss * (1.0f/256.0f) - mean*mean;
  float rstd = rsqrtf(var + 1e-5f);
  float4 gv = ((const float4*)g)[lane], bv = ((const float4*)b)[lane];
  float4 r;
  r.x = (v.x-mean)*rstd*gv.x + bv.x;
  r.y = (v.y-mean)*rstd*gv.y + bv.y;
  r.z = (v.z-mean)*rstd*gv.z + bv.z;
  r.w = (v.w-mean)*rstd*gv.w + bv.w;
  ((float4*)(o + t * 256))[lane] = r;
}

// ---------------- Attention: one block (512 thr) per window ----------------
// Per head: q,k,v (64x32) computed on the fly from xnorm (global, L1/L2-hot),
// scores+softmax+PV in LDS. ce from own window's cor.
__global__ __launch_bounds__(512) void k_attn(const float* __restrict__ xnorm,
    const float* __restrict__ cor,
    const float* __restrict__ Wq,  const float* __restrict__ bq,
    const float* __restrict__ Wkv, const float* __restrict__ bkv,
    const float* __restrict__ Wce, const float* __restrict__ bce,
    float* __restrict__ af, float* __restrict__ mfraw) {
  __shared__ __attribute__((aligned(16))) float sQ[64*33];
  __shared__ __attribute__((aligned(16))) float sK[64*33];
  __shared__ __attribute__((aligned(16))) float sV[64*33];
  __shared__ __attribute__((aligned(16))) float sCE[64*17];
  __shared__ __attribute__((aligned(16))) float sS[64*65];
  const int tid = threadIdx.x;
  const int w = blockIdx.x;                 // 0..2047
  const int b = w >> 8, widx = w & 255;
  const int wh = widx >> 4, ww = widx & 15;
  const int bp = (b + 4) & 7;
  const int rowbase = wh*8*128 + ww*8;

  const int d = tid & 31;                   // head-dim lane
  const int i0 = tid >> 5;                  // 0..15
  const float scale = 0.1767766952966369f;  // 32^-0.5

  // row pointers for this thread's 4 query rows (own + partner), head-invariant
  const float4* xr[4]; const float4* xpr[4]; int tokr[4];
  #pragma unroll
  for (int j = 0; j < 4; ++j) {
    int i = i0 + j*16;
    int t  = b*16384  + rowbase + (i>>3)*128 + (i&7);
    int tp = bp*16384 + rowbase + (i>>3)*128 + (i&7);
    tokr[j] = t;
    xr[j]  = (const float4*)(xnorm + (size_t)t  * 256);
    xpr[j] = (const float4*)(xnorm + (size_t)tp * 256);
  }

  for (int h = 0; h < 8; ++h) {
    const int cq = h*32 + d;
    // ---- q (own), k,v (partner) ----
    float aq[4], ak[4], av[4];
    {
      float bqv = bq[cq], bkvv = bkv[cq], bvv = bkv[256+cq];
      #pragma unroll
      for (int j = 0; j < 4; ++j) { aq[j] = bqv; ak[j] = bkvv; av[j] = bvv; }
    }
    const float* wqp = Wq + cq;
    const float* wkp = Wkv + cq;
    const float* wvp = Wkv + 256 + cq;
    #pragma unroll 2
    for (int c4 = 0; c4 < 64; ++c4) {
      int c = c4*4;
      float wq0 = wqp[(c+0)*256], wq1 = wqp[(c+1)*256], wq2 = wqp[(c+2)*256], wq3 = wqp[(c+3)*256];
      float wk0 = wkp[(c+0)*512], wk1 = wkp[(c+1)*512], wk2 = wkp[(c+2)*512], wk3 = wkp[(c+3)*512];
      float wv0 = wvp[(c+0)*512], wv1 = wvp[(c+1)*512], wv2 = wvp[(c+2)*512], wv3 = wvp[(c+3)*512];
      #pragma unroll
      for (int j = 0; j < 4; ++j) {
        float4 xa = xr[j][c4];
        float4 xb = xpr[j][c4];
        aq[j] += xa.x*wq0 + xa.y*wq1 + xa.z*wq2 + xa.w*wq3;
        ak[j] += xb.x*wk0 + xb.y*wk1 + xb.z*wk2 + xb.w*wk3;
        av[j] += xb.x*wv0 + xb.y*wv1 + xb.z*wv2 + xb.w*wv3;
      }
    }
    #pragma unroll
    for (int j = 0; j < 4; ++j) {
      int i = i0 + j*16;
      sQ[i*33+d] = aq[j]; sK[i*33+d] = ak[j]; sV[i*33+d] = av[j];
    }
    // ---- ce (own window coords) ----
    for (int e = tid; e < 1024; e += 512) {
      int i = e >> 4, dd = e & 15;
      int t = b*16384 + rowbase + (i>>3)*128 + (i&7);
      float cx = cor[(size_t)t*2], cy = cor[(size_t)t*2+1];
      int cc = h*16 + dd;
      sCE[i*17+dd] = cx*Wce[cc] + cy*Wce[128+cc] + bce[cc];
    }
    __syncthreads();
    // ---- S = scale * q k^T ----
    for (int e = tid; e < 4096; e += 512) {
      int i = e >> 6, jj = e & 63;
      float acc = 0.0f;
      #pragma unroll
      for (int dd = 0; dd < 32; ++dd) acc += sQ[i*33+dd]*sK[jj*33+dd];
      sS[i*65+jj] = acc * scale;
    }
    __syncthreads();
    // ---- softmax rows ----
    if (tid < 64) {
      float m = -1e30f;
      for (int jj = 0; jj < 64; ++jj) m = fmaxf(m, sS[tid*65+jj]);
      float sum = 0.0f;
      for (int jj = 0; jj < 64; ++jj) { float p = __expf(sS[tid*65+jj]-m); sS[tid*65+jj] = p; sum += p; }
      float inv = 1.0f / sum;
      for (int jj = 0; jj < 64; ++jj) sS[tid*65+jj] *= inv;
    }
    __syncthreads();
    // ---- af = P v ; mf = P ce ----
    for (int e = tid; e < 2048; e += 512) {
      int i = e >> 5, dd = e & 31;
      float acc = 0.0f;
      #pragma unroll
      for (int jj = 0; jj < 64; ++jj) acc += sS[i*65+jj]*sV[jj*33+dd];
      int t = b*16384 + rowbase + (i>>3)*128 + (i&7);
      af[(size_t)t*256 + h*32 + dd] = acc;
    }
    for (int e = tid; e < 1024; e += 512) {
      int i = e >> 4, dd = e & 15;
      float acc = 0.0f;
      #pragma unroll
      for (int jj = 0; jj < 64; ++jj) acc += sS[i*65+jj]*sCE[jj*17+dd];
      int t = b*16384 + rowbase + (i>>3)*128 + (i&7);
      mfraw[(size_t)t*128 + h*16 + dd] = acc;
    }
    __syncthreads();
  }
  (void)tokr;
}

// ---------------- proj: xout = xnorm + af @ Wproj + bproj ----------------
__global__ __launch_bounds__(256) void k_proj(const float* __restrict__ X,
    const float* __restrict__ W, const float* __restrict__ bias,
    const float* __restrict__ res, float* __restrict__ out) {
  __shared__ __attribute__((aligned(16))) float Xt[64][33];
  __shared__ __attribute__((aligned(16))) float Wt[32][256];
  int tid = threadIdx.x;
  size_t tb = (size_t)blockIdx.x * 64;
  int ir = tid >> 2, cg = tid & 3, c0 = cg * 64;
  float4 acc[16];
  #pragma unroll
  for (int j = 0; j < 16; ++j) acc[j] = make_float4(0.f,0.f,0.f,0.f);
  for (int kt = 0; kt < 256; kt += 32) {
    __syncthreads();
    for (int e = tid; e < 2048; e += 256) { int r = e>>5, c = e&31;
      Xt[r][c] = X[(tb + r)*256 + kt + c]; }
    for (int e = tid; e < 8192; e += 256) { int r = e>>8, c = e&255;
      Wt[r][c] = W[(size_t)(kt + r)*256 + c]; }
    __syncthreads();
    #pragma unroll 4
    for (int kk = 0; kk < 32; ++kk) {
      float a = Xt[ir][kk];
      const float4* wr = (const float4*)&Wt[kk][c0];
      #pragma unroll
      for (int j = 0; j < 16; ++j) {
        float4 w = wr[j];
        acc[j].x += a*w.x; acc[j].y += a*w.y; acc[j].z += a*w.z; acc[j].w += a*w.w;
      }
    }
  }
  size_t rowo = (tb + ir)*256 + c0;
  const float4* b4 = (const float4*)(bias + c0);
  const float4* r4 = (const float4*)(res + rowo);
  float4* o4 = (float4*)(out + rowo);
  #pragma unroll
  for (int j = 0; j < 16; ++j) {
    float4 v = acc[j]; float4 bb = b4[j]; float4 rr = r4[j];
    v.x += bb.x + rr.x; v.y += bb.y + rr.y; v.z += bb.z + rr.z; v.w += bb.w + rr.w;
    o4[j] = v;
  }
}

// ------------- motion: mout = (mfraw - ce) @ Wmp + bmp -------------
__global__ __launch_bounds__(256) void k_motion(const float* __restrict__ X,
    const float* __restrict__ cor, const float* __restrict__ Wce,
    const float* __restrict__ bce, const float* __restrict__ W,
    const float* __restrict__ bias, float* __restrict__ out) {
  __shared__ __attribute__((aligned(16))) float Xt[64][33];
  __shared__ __attribute__((aligned(16))) float Wt[32][128];
  int tid = threadIdx.x;
  size_t tb = (size_t)blockIdx.x * 64;
  int ir = tid >> 2, cg = tid & 3, c0 = cg * 32;
  float4 acc[8];
  #pragma unroll
  for (int j = 0; j < 8; ++j) acc[j] = make_float4(0.f,0.f,0.f,0.f);
  for (int kt = 0; kt < 128; kt += 32) {
    __syncthreads();
    for (int e = tid; e < 2048; e += 256) {
      int r = e>>5, c = e&31; int k = kt + c;
      size_t t = tb + r;
      float cx = cor[t*2], cy = cor[t*2+1];
      Xt[r][c] = X[t*128 + k] - (cx*Wce[k] + cy*Wce[128+k] + bce[k]);
    }
    for (int e = tid; e < 4096; e += 256) { int r = e>>7, c = e&127;
      Wt[r][c] = W[(size_t)(kt + r)*128 + c]; }
    __syncthreads();
    #pragma unroll 4
    for (int kk = 0; kk < 32; ++kk) {
      float a = Xt[ir][kk];
      const float4* wr = (const float4*)&Wt[kk][c0];
      #pragma unroll
      for (int j = 0; j < 8; ++j) {
        float4 w = wr[j];
        acc[j].x += a*w.x; acc[j].y += a*w.y; acc[j].z += a*w.z; acc[j].w += a*w.w;
      }
    }
  }
  size_t rowo = (tb + ir)*128 + c0;
  const float4* b4 = (const float4*)(bias + c0);
  float4* o4 = (float4*)(out + rowo);
  #pragma unroll
  for (int j = 0; j < 8; ++j) {
    float4 v = acc[j]; float4 bb = b4[j];
    v.x += bb.x; v.y += bb.y; v.z += bb.z; v.w += bb.w;
    o4[j] = v;
  }
}

// ------------- fc1 with fused LN2: h1 = (LN(xo)*g+b) @ Wfc1 + bfc1 (bf16 out) -------------
__global__ __launch_bounds__(256) void k_fc1(const float* __restrict__ xo,
    const float* __restrict__ g, const float* __restrict__ bln,
    const float* __restrict__ W, const float* __restrict__ bias,
    unsigned short* __restrict__ h1) {
  __shared__ __attribute__((aligned(16))) float Xt[64][33];
  __shared__ __attribute__((aligned(16))) float Wt[32][256];
  __shared__ float red[64][8];
  __shared__ float mArr[64], rsArr[64];
  int tid = threadIdx.x;
  size_t tb = (size_t)blockIdx.x * 64;
  int cb = blockIdx.y * 256;
  int ir = tid >> 2, cg = tid & 3, c0 = cg * 64;
  // LN stats over the 256 channels (coalesced via staged tiles)
  float ps = 0.f, pss = 0.f;
  for (int kt = 0; kt < 256; kt += 32) {
    __syncthreads();
    for (int e = tid; e < 2048; e += 256) { int r = e>>5, c = e&31;
      Xt[r][c] = xo[(tb + r)*256 + kt + c]; }
    __syncthreads();
    #pragma unroll
    for (int j = 0; j < 8; ++j) { float v = Xt[ir][cg*8+j]; ps += v; pss += v*v; }
  }
  red[ir][cg] = ps; red[ir][4+cg] = pss;
  __syncthreads();
  if (tid < 64) {
    float s  = red[tid][0]+red[tid][1]+red[tid][2]+red[tid][3];
    float ss = red[tid][4]+red[tid][5]+red[tid][6]+red[tid][7];
    float m = s * (1.0f/256.0f);
    float var = ss * (1.0f/256.0f) - m*m;
    mArr[tid] = m; rsArr[tid] = rsqrtf(var + 1e-5f);
  }
  float4 acc[16];
  #pragma unroll
  for (int j = 0; j < 16; ++j) acc[j] = make_float4(0.f,0.f,0.f,0.f);
  for (int kt = 0; kt < 256; kt += 32) {
    __syncthreads();
    for (int e = tid; e < 2048; e += 256) {
      int r = e>>5, c = e&31; int k = kt + c;
      Xt[r][c] = (xo[(tb + r)*256 + k] - mArr[r]) * rsArr[r] * g[k] + bln[k];
    }
    for (int e = tid; e < 8192; e += 256) { int r = e>>8, c = e&255;
      Wt[r][c] = W[(size_t)(kt + r)*1024 + cb + c]; }
    __syncthreads();
    #pragma unroll 4
    for (int kk = 0; kk < 32; ++kk) {
      float a = Xt[ir][kk];
      const float4* wr = (const float4*)&Wt[kk][c0];
      #pragma unroll
      for (int j = 0; j < 16; ++j) {
        float4 w = wr[j];
        acc[j].x += a*w.x; acc[j].y += a*w.y; acc[j].z += a*w.z; acc[j].w += a*w.w;
      }
    }
  }
  size_t rowo = (tb + ir)*1024 + cb + c0;
  #pragma unroll
  for (int j = 0; j < 16; ++j) {
    float4 v = acc[j];
    const float4 bb = *(const float4*)(bias + cb + c0 + j*4);
    v.x += bb.x; v.y += bb.y; v.z += bb.z; v.w += bb.w;
    uint2 p;
    p.x = (unsigned)f2bfbits(v.x) | ((unsigned)f2bfbits(v.y) << 16);
    p.y = (unsigned)f2bfbits(v.z) | ((unsigned)f2bfbits(v.w) << 16);
    *(uint2*)(h1 + rowo + j*4) = p;
  }
}

// ------------- depthwise 3x3 SAME (per image) + bias + exact gelu -------------
__global__ __launch_bounds__(256) void k_conv(const unsigned short* __restrict__ h1,
    const float* __restrict__ Wdw, const float* __restrict__ bdw,
    unsigned short* __restrict__ h2) {
  size_t e = (size_t)blockIdx.x * 256 + threadIdx.x;   // < 131072*256
  int t = (int)(e >> 8);
  int gch = (int)(e & 255) * 4;
  int b = t >> 14, tl = t & 16383;
  int row = tl >> 7, col = tl & 127;
  const float4 bb = *(const float4*)(bdw + gch);
  float a0 = bb.x, a1 = bb.y, a2 = bb.z, a3 = bb.w;
  #pragma unroll
  for (int kr = 0; kr < 3; ++kr) {
    int r2 = row + kr - 1;
    if ((unsigned)r2 > 127u) continue;
    #pragma unroll
    for (int kc = 0; kc < 3; ++kc) {
      int c2 = col + kc - 1;
      if ((unsigned)c2 > 127u) continue;
      const unsigned short* p = h1 + (((size_t)b*16384 + r2*128 + c2)*1024 + gch);
      uint2 raw = *(const uint2*)p;
      float x0 = __uint_as_float(raw.x << 16);
      float x1 = __uint_as_float(raw.x & 0xffff0000u);
      float x2 = __uint_as_float(raw.y << 16);
      float x3 = __uint_as_float(raw.y & 0xffff0000u);
      const float4 wv = *(const float4*)(Wdw + (kr*3 + kc)*1024 + gch);
      a0 += x0*wv.x; a1 += x1*wv.y; a2 += x2*wv.z; a3 += x3*wv.w;
    }
  }
  const float k = 0.70710678118654752440f;
  a0 = 0.5f*a0*(1.0f + erff(a0*k));
  a1 = 0.5f*a1*(1.0f + erff(a1*k));
  a2 = 0.5f*a2*(1.0f + erff(a2*k));
  a3 = 0.5f*a3*(1.0f + erff(a3*k));
  uint2 o;
  o.x = (unsigned)f2bfbits(a0) | ((unsigned)f2bfbits(a1) << 16);
  o.y = (unsigned)f2bfbits(a2) | ((unsigned)f2bfbits(a3) << 16);
  *(uint2*)(h2 + (size_t)t*1024 + gch) = o;
}

// ------------- fc2 + residual into d_out -------------
__global__ __launch_bounds__(256) void k_fc2(const unsigned short* __restrict__ h2,
    const float* __restrict__ W, const float* __restrict__ bias,
    float* __restrict__ xo) {
  __shared__ __attribute__((aligned(16))) float Xt[64][33];
  __shared__ __attribute__((aligned(16))) float Wt[32][256];
  int tid = threadIdx.x;
  size_t tb = (size_t)blockIdx.x * 64;
  int ir = tid >> 2, cg = tid & 3, c0 = cg * 64;
  float4 acc[16];
  #pragma unroll
  for (int j = 0; j < 16; ++j) acc[j] = make_float4(0.f,0.f,0.f,0.f);
  for (int kt = 0; kt < 1024; kt += 32) {
    __syncthreads();
    for (int e = tid; e < 2048; e += 256) { int r = e>>5, c = e&31;
      Xt[r][c] = bfbits2f(h2[(tb + r)*1024 + kt + c]); }
    for (int e = tid; e < 8192; e += 256) { int r = e>>8, c = e&255;
      Wt[r][c] = W[(size_t)(kt + r)*256 + c]; }
    __syncthreads();
    #pragma unroll 4
    for (int kk = 0; kk < 32; ++kk) {
      float a = Xt[ir][kk];
      const float4* wr = (const float4*)&Wt[kk][c0];
      #pragma unroll
      for (int j = 0; j < 16; ++j) {
        float4 w = wr[j];
        acc[j].x += a*w.x; acc[j].y += a*w.y; acc[j].z += a*w.z; acc[j].w += a*w.w;
      }
    }
  }
  size_t rowo = (tb + ir)*256 + c0;
  const float4* b4 = (const float4*)(bias + c0);
  float4* o4 = (float4*)(xo + rowo);
  #pragma unroll
  for (int j = 0; j < 16; ++j) {
    float4 v = acc[j]; float4 bb = b4[j]; float4 rr = o4[j];
    v.x += bb.x + rr.x; v.y += bb.y + rr.y; v.z += bb.z + rr.z; v.w += bb.w + rr.w;
    o4[j] = v;
  }
}

extern "C" void kernel_launch(void* const* d_in, const int* in_sizes, int n_in,
                              void* d_out, int out_size, void* d_ws, size_t ws_size,
                              hipStream_t stream) {
  const float* x     = (const float*)d_in[0];
  const float* cor   = (const float*)d_in[1];
  const float* g1    = (const float*)d_in[2];
  const float* b1    = (const float*)d_in[3];
  const float* Wq    = (const float*)d_in[4];
  const float* bq    = (const float*)d_in[5];
  const float* Wkv   = (const float*)d_in[6];
  const float* bkv   = (const float*)d_in[7];
  const float* Wproj = (const float*)d_in[8];
  const float* bproj = (const float*)d_in[9];
  const float* Wce   = (const float*)d_in[10];
  const float* bce   = (const float*)d_in[11];
  const float* Wmp   = (const float*)d_in[12];
  const float* bmp   = (const float*)d_in[13];
  const float* g2    = (const float*)d_in[14];
  const float* b2    = (const float*)d_in[15];
  const float* Wfc1  = (const float*)d_in[16];
  const float* bfc1  = (const float*)d_in[17];
  const float* Wdw   = (const float*)d_in[18];
  const float* bdw   = (const float*)d_in[19];
  const float* Wfc2  = (const float*)d_in[20];
  const float* bfc2  = (const float*)d_in[21];

  float* xout = (float*)d_out;                       // 33554432 floats
  float* mout = xout + (size_t)NTOK * DIM;           // 16777216 floats

  char* ws = (char*)d_ws;
  float* xnorm = (float*)(ws);
  float* afb   = (float*)(ws + 134217728);
  float* mfb   = (float*)(ws + 268435456);
  unsigned short* h1 = (unsigned short*)(ws);               // aliases xnorm+af (dead)
  unsigned short* h2 = (unsigned short*)(ws + 268435456);   // aliases mfraw (dead)

  k_ln1<<<dim3(NTOK/4), dim3(256), 0, stream>>>(x, g1, b1, xnorm);
  k_attn<<<dim3(2048), dim3(512), 0, stream>>>(xnorm, cor, Wq, bq, Wkv, bkv,
                                               Wce, bce, afb, mfb);
  k_proj<<<dim3(NTOK/64), dim3(256), 0, stream>>>(afb, Wproj, bproj, xnorm, xout);
  k_motion<<<dim3(NTOK/64), dim3(256), 0, stream>>>(mfb, cor, Wce, bce, Wmp, bmp, mout);
  k_fc1<<<dim3(NTOK/64, 4), dim3(256), 0, stream>>>(xout, g2, b2, Wfc1, bfc1, h1);
  k_conv<<<dim3(NTOK), dim3(256), 0, stream>>>(h1, Wdw, bdw, h2);
  k_fc2<<<dim3(NTOK/64), dim3(256), 0, stream>>>(h2, Wfc2, bfc2, xout);
}

// Round 2
// 1828.580 us; speedup vs baseline: 8.1176x; 8.1176x over previous
//
#include <hip/hip_runtime.h>
#include <hip/hip_bf16.h>

// MotionFormerBlock MI355X — Round 2: bf16 MFMA GEMMs everywhere.
// Pipeline: wprep×5, ln1 -> Q gemm, KV gemm -> attn core -> proj gemm(+res)
//           -> motion gemm -> ln2 -> fc1 gemm -> conv -> wprep(fc2) -> fc2 gemm(rmw)
//
// ws layout (bytes), peak exactly 536870912:
//  [0,        67108864)  xnorm_bf  (dead after proj)   } h1 [0, 268435456)
//  [67108864, 134217728) q_bf      (dead after attn)   }   after proj
//  [134217728,268435456) kv_bf     (dead after attn)   }   Wfc2t [0,524288) after conv
//  [268435456,335544320) af_bf     (dead after proj)   } h2 [268435456, 536870912)
//  [335544320,369098752) mdiff     (dead after motion) }   after motion/fc1
//  [369098752,436207616) xn2       (dead after fc1)    }
//  [436207616,437288960) bf16 weights (all used before conv)

#define NTOK 131072

using bf16x8 = __attribute__((ext_vector_type(8))) short;
using f32x4  = __attribute__((ext_vector_type(4))) float;

static __device__ __forceinline__ unsigned f2bfbits(float f) {
  __hip_bfloat16 h = __float2bfloat16(f);
  return (unsigned)*reinterpret_cast<unsigned short*>(&h);
}
static __device__ __forceinline__ float bfbits2f(unsigned short u) {
  return __uint_as_float(((unsigned)u) << 16);
}
static __device__ __forceinline__ void gld16(const void* g, void* l) {
  __builtin_amdgcn_global_load_lds(
      (const __attribute__((address_space(1))) void*)g,
      (__attribute__((address_space(3))) void*)l, 16, 0, 0);
}

// ---- weight prep: fp32 KxN -> bf16 NxK (transpose) ----
__global__ __launch_bounds__(256) void k_wt(const float* __restrict__ in,
    unsigned short* __restrict__ out, int K, int N) {
  int n = blockIdx.y * 256 + threadIdx.x;
  int k = blockIdx.x;
  if (n < N) out[(size_t)n * K + k] = (unsigned short)f2bfbits(in[(size_t)k * N + n]);
}

// ---- LN1: x fp32 -> bf16 ----
__global__ __launch_bounds__(256) void k_ln1(const float* __restrict__ x,
    const float* __restrict__ g, const float* __restrict__ b,
    unsigned short* __restrict__ o) {
  int lane = threadIdx.x & 63;
  size_t t = (size_t)blockIdx.x * 4 + (threadIdx.x >> 6);
  float4 v = ((const float4*)(x + t * 256))[lane];
  float s = v.x + v.y + v.z + v.w;
  float ss = v.x*v.x + v.y*v.y + v.z*v.z + v.w*v.w;
  #pragma unroll
  for (int m = 32; m; m >>= 1) { s += __shfl_xor(s, m, 64); ss += __shfl_xor(ss, m, 64); }
  float mean = s * (1.0f/256.0f);
  float var = ss * (1.0f/256.0f) - mean*mean;
  float rstd = rsqrtf(var + 1e-5f);
  float4 gv = ((const float4*)g)[lane], bv = ((const float4*)b)[lane];
  uint2 p;
  p.x = f2bfbits((v.x-mean)*rstd*gv.x + bv.x) | (f2bfbits((v.y-mean)*rstd*gv.y + bv.y) << 16);
  p.y = f2bfbits((v.z-mean)*rstd*gv.z + bv.z) | (f2bfbits((v.w-mean)*rstd*gv.w + bv.w) << 16);
  *(uint2*)(o + t * 256 + lane * 4) = p;
}

// ---- LN2: xout fp32 -> bf16 (same math, different src) ----
__global__ __launch_bounds__(256) void k_ln2(const float* __restrict__ x,
    const float* __restrict__ g, const float* __restrict__ b,
    unsigned short* __restrict__ o) {
  int lane = threadIdx.x & 63;
  size_t t = (size_t)blockIdx.x * 4 + (threadIdx.x >> 6);
  float4 v = ((const float4*)(x + t * 256))[lane];
  float s = v.x + v.y + v.z + v.w;
  float ss = v.x*v.x + v.y*v.y + v.z*v.z + v.w*v.w;
  #pragma unroll
  for (int m = 32; m; m >>= 1) { s += __shfl_xor(s, m, 64); ss += __shfl_xor(ss, m, 64); }
  float mean = s * (1.0f/256.0f);
  float var = ss * (1.0f/256.0f) - mean*mean;
  float rstd = rsqrtf(var + 1e-5f);
  float4 gv = ((const float4*)g)[lane], bv = ((const float4*)b)[lane];
  uint2 p;
  p.x = f2bfbits((v.x-mean)*rstd*gv.x + bv.x) | (f2bfbits((v.y-mean)*rstd*gv.y + bv.y) << 16);
  p.y = f2bfbits((v.z-mean)*rstd*gv.z + bv.z) | (f2bfbits((v.w-mean)*rstd*gv.w + bv.w) << 16);
  *(uint2*)(o + t * 256 + lane * 4) = p;
}

// ---- MFMA GEMM: C[M,N] = A[M,K]bf16 @ Bt[N,K]bf16^T, 128x128 tile ----
// EPI: 0 = bf16 out + bias; 1 = fp32 out = acc+bias+bf16res; 2 = fp32 out = acc+bias;
//      3 = fp32 out += acc+bias
template<int EPI>
__global__ __launch_bounds__(256) void k_gemm(
    const unsigned short* __restrict__ A, const unsigned short* __restrict__ Bt,
    const float* __restrict__ bias, const unsigned short* __restrict__ resb,
    float* __restrict__ outf, unsigned short* __restrict__ outb, int K, int N) {
  __shared__ __attribute__((aligned(16))) unsigned short sA[128 * 32];
  __shared__ __attribute__((aligned(16))) unsigned short sB[128 * 32];
  const int tid = threadIdx.x;
  const int m0 = blockIdx.x << 7, n0 = blockIdx.y << 7;
  const int wid = tid >> 6, lane = tid & 63, quad = lane >> 4, ln = lane & 15;
  const int wm = (wid & 1) << 6, wn = (wid >> 1) << 6;

  const unsigned short* ga = A + (size_t)(m0 + (tid >> 2)) * K + (tid & 3) * 8;
  const unsigned short* gb = Bt + (size_t)(n0 + (tid >> 2)) * K + (tid & 3) * 8;
  unsigned short* la = sA + tid * 8;
  unsigned short* lb = sB + tid * 8;
  const size_t gstep = (size_t)64 * K;

  f32x4 acc[4][4];
  #pragma unroll
  for (int i = 0; i < 4; ++i)
    #pragma unroll
    for (int j = 0; j < 4; ++j) acc[i][j] = (f32x4)0.0f;

  for (int kt = 0; kt < K; kt += 32) {
    gld16(ga, la);            gld16(ga + gstep, la + 2048);
    gld16(gb, lb);            gld16(gb + gstep, lb + 2048);
    ga += 32; gb += 32;
    __syncthreads();
    bf16x8 afr[4], bfr[4];
    #pragma unroll
    for (int i = 0; i < 4; ++i) {
      afr[i] = *(const bf16x8*)(sA + (wm + i*16 + ln) * 32 + quad * 8);
      bfr[i] = *(const bf16x8*)(sB + (wn + i*16 + ln) * 32 + quad * 8);
    }
    #pragma unroll
    for (int i = 0; i < 4; ++i)
      #pragma unroll
      for (int j = 0; j < 4; ++j)
        acc[i][j] = __builtin_amdgcn_mfma_f32_16x16x32_bf16(afr[i], bfr[j], acc[i][j], 0, 0, 0);
    __syncthreads();
  }

  #pragma unroll
  for (int j = 0; j < 4; ++j) {
    int col = n0 + wn + j*16 + ln;
    float bv = bias[col];
    #pragma unroll
    for (int i = 0; i < 4; ++i) {
      int rowb = m0 + wm + i*16 + quad*4;
      #pragma unroll
      for (int r = 0; r < 4; ++r) {
        float v = acc[i][j][r] + bv;
        size_t off = (size_t)(rowb + r) * N + col;
        if (EPI == 0)      outb[off] = (unsigned short)f2bfbits(v);
        else if (EPI == 1) outf[off] = v + bfbits2f(resb[off]);
        else if (EPI == 2) outf[off] = v;
        else               outf[off] += v;
      }
    }
  }
}

// ---- attention core: one block (512 thr) per window ----
__global__ __launch_bounds__(512) void k_attn2(
    const unsigned short* __restrict__ q, const unsigned short* __restrict__ kv,
    const float* __restrict__ cor, const float* __restrict__ Wce,
    const float* __restrict__ bce, unsigned short* __restrict__ af,
    unsigned short* __restrict__ mdiff) {
  __shared__ __attribute__((aligned(16))) float sQ[64*36];
  __shared__ __attribute__((aligned(16))) float sK[64*36];
  __shared__ __attribute__((aligned(16))) float sV[64*36];
  __shared__ __attribute__((aligned(16))) float sCE[64*20];
  __shared__ __attribute__((aligned(16))) float sS[64*68];
  __shared__ float sCor[128];
  const int tid = threadIdx.x;
  const int w = blockIdx.x, b = w >> 8, widx = w & 255;
  const int base = b*16384 + (widx >> 4)*1024 + (widx & 15)*8;
  if (tid < 128) {
    int i = tid >> 1, c = tid & 1;
    int t = base + ((i >> 3) << 7) + (i & 7);
    sCor[tid] = cor[(size_t)t*2 + c];
  }
  __syncthreads();
  const int si = tid >> 3, sg = tid & 7;
  const int tso = base + ((si >> 3) << 7) + (si & 7);   // own token for compute rows
  const float scale = 0.1767766952966369f;

  for (int h = 0; h < 8; ++h) {
    #pragma unroll
    for (int e0 = 0; e0 < 4; ++e0) {
      int e = tid + e0*512;
      int i = e >> 5, d = e & 31;
      int t = base + ((i >> 3) << 7) + (i & 7);
      int tp = t ^ 65536;
      sQ[i*36 + d] = bfbits2f(q[(size_t)t*256 + h*32 + d]);
      sK[i*36 + d] = bfbits2f(kv[(size_t)tp*512 + h*32 + d]);
      sV[i*36 + d] = bfbits2f(kv[(size_t)tp*512 + 256 + h*32 + d]);
    }
    #pragma unroll
    for (int e0 = 0; e0 < 2; ++e0) {
      int e = tid + e0*512;
      int i = e >> 4, dd = e & 15;
      int c = h*16 + dd;
      sCE[i*20 + dd] = sCor[i*2]*Wce[c] + sCor[i*2+1]*Wce[128 + c] + bce[c];
    }
    __syncthreads();
    // S row si, cols sg*8..sg*8+7
    float accs[8];
    #pragma unroll
    for (int j = 0; j < 8; ++j) accs[j] = 0.f;
    const float4* qr = (const float4*)(sQ + si*36);
    #pragma unroll
    for (int dd4 = 0; dd4 < 8; ++dd4) {
      float4 qv = qr[dd4];
      #pragma unroll
      for (int j = 0; j < 8; ++j) {
        float4 kvv = *(const float4*)(sK + (sg*8 + j)*36 + dd4*4);
        accs[j] += qv.x*kvv.x + qv.y*kvv.y + qv.z*kvv.z + qv.w*kvv.w;
      }
    }
    float mx = -1e30f;
    #pragma unroll
    for (int j = 0; j < 8; ++j) { accs[j] *= scale; mx = fmaxf(mx, accs[j]); }
    mx = fmaxf(mx, __shfl_xor(mx, 1, 64));
    mx = fmaxf(mx, __shfl_xor(mx, 2, 64));
    mx = fmaxf(mx, __shfl_xor(mx, 4, 64));
    float sum = 0.f;
    #pragma unroll
    for (int j = 0; j < 8; ++j) { accs[j] = __expf(accs[j] - mx); sum += accs[j]; }
    sum += __shfl_xor(sum, 1, 64);
    sum += __shfl_xor(sum, 2, 64);
    sum += __shfl_xor(sum, 4, 64);
    float inv = 1.0f / sum;
    #pragma unroll
    for (int j = 0; j < 8; ++j) sS[si*68 + sg*8 + j] = accs[j] * inv;
    __syncthreads();
    // af = P v : row si, dims sg*4..+3
    {
      float ax=0.f, ay=0.f, az=0.f, aw=0.f;
      const float* srow = sS + si*68;
      #pragma unroll 8
      for (int jj = 0; jj < 64; ++jj) {
        float s = srow[jj];
        float4 vv = *(const float4*)(sV + jj*36 + sg*4);
        ax += s*vv.x; ay += s*vv.y; az += s*vv.z; aw += s*vv.w;
      }
      uint2 p;
      p.x = f2bfbits(ax) | (f2bfbits(ay) << 16);
      p.y = f2bfbits(az) | (f2bfbits(aw) << 16);
      *(uint2*)(af + (size_t)tso*256 + h*32 + sg*4) = p;
    }
    // mdiff = P ce - ce : row si, dims sg*2..+1
    {
      float a0=0.f, a1=0.f;
      const float* srow = sS + si*68;
      #pragma unroll 8
      for (int jj = 0; jj < 64; ++jj) {
        float s = srow[jj];
        float2 cv = *(const float2*)(sCE + jj*20 + sg*2);
        a0 += s*cv.x; a1 += s*cv.y;
      }
      a0 -= sCE[si*20 + sg*2];
      a1 -= sCE[si*20 + sg*2 + 1];
      unsigned pp = f2bfbits(a0) | (f2bfbits(a1) << 16);
      *(unsigned*)(mdiff + (size_t)tso*128 + h*16 + sg*2) = pp;
    }
    __syncthreads();
  }
}

// ---- depthwise 3x3 SAME + bias + exact gelu (bf16 in/out) ----
__global__ __launch_bounds__(256) void k_conv(const unsigned short* __restrict__ h1,
    const float* __restrict__ Wdw, const float* __restrict__ bdw,
    unsigned short* __restrict__ h2) {
  size_t e = (size_t)blockIdx.x * 256 + threadIdx.x;
  int t = (int)(e >> 8);
  int gch = (int)(e & 255) * 4;
  int b = t >> 14, tl = t & 16383;
  int row = tl >> 7, col = tl & 127;
  const float4 bb = *(const float4*)(bdw + gch);
  float a0 = bb.x, a1 = bb.y, a2 = bb.z, a3 = bb.w;
  #pragma unroll
  for (int kr = 0; kr < 3; ++kr) {
    int r2 = row + kr - 1;
    if ((unsigned)r2 > 127u) continue;
    #pragma unroll
    for (int kc = 0; kc < 3; ++kc) {
      int c2 = col + kc - 1;
      if ((unsigned)c2 > 127u) continue;
      const unsigned short* p = h1 + (((size_t)b*16384 + r2*128 + c2)*1024 + gch);
      uint2 raw = *(const uint2*)p;
      float x0 = __uint_as_float(raw.x << 16);
      float x1 = __uint_as_float(raw.x & 0xffff0000u);
      float x2 = __uint_as_float(raw.y << 16);
      float x3 = __uint_as_float(raw.y & 0xffff0000u);
      const float4 wv = *(const float4*)(Wdw + (kr*3 + kc)*1024 + gch);
      a0 += x0*wv.x; a1 += x1*wv.y; a2 += x2*wv.z; a3 += x3*wv.w;
    }
  }
  const float k = 0.70710678118654752440f;
  a0 = 0.5f*a0*(1.0f + erff(a0*k));
  a1 = 0.5f*a1*(1.0f + erff(a1*k));
  a2 = 0.5f*a2*(1.0f + erff(a2*k));
  a3 = 0.5f*a3*(1.0f + erff(a3*k));
  uint2 o;
  o.x = f2bfbits(a0) | (f2bfbits(a1) << 16);
  o.y = f2bfbits(a2) | (f2bfbits(a3) << 16);
  *(uint2*)(h2 + (size_t)t*1024 + gch) = o;
}

extern "C" void kernel_launch(void* const* d_in, const int* in_sizes, int n_in,
                              void* d_out, int out_size, void* d_ws, size_t ws_size,
                              hipStream_t stream) {
  const float* x     = (const float*)d_in[0];
  const float* cor   = (const float*)d_in[1];
  const float* g1    = (const float*)d_in[2];
  const float* b1    = (const float*)d_in[3];
  const float* Wq    = (const float*)d_in[4];
  const float* bq    = (const float*)d_in[5];
  const float* Wkv   = (const float*)d_in[6];
  const float* bkv   = (const float*)d_in[7];
  const float* Wproj = (const float*)d_in[8];
  const float* bproj = (const float*)d_in[9];
  const float* Wce   = (const float*)d_in[10];
  const float* bce   = (const float*)d_in[11];
  const float* Wmp   = (const float*)d_in[12];
  const float* bmp   = (const float*)d_in[13];
  const float* g2    = (const float*)d_in[14];
  const float* b2    = (const float*)d_in[15];
  const float* Wfc1  = (const float*)d_in[16];
  const float* bfc1  = (const float*)d_in[17];
  const float* Wdw   = (const float*)d_in[18];
  const float* bdw   = (const float*)d_in[19];
  const float* Wfc2  = (const float*)d_in[20];
  const float* bfc2  = (const float*)d_in[21];

  float* xout = (float*)d_out;
  float* mout = xout + (size_t)NTOK * 256;

  unsigned short* ws16   = (unsigned short*)d_ws;
  unsigned short* xnormb = ws16;                 // 33554432 el
  unsigned short* qb     = ws16 + 33554432;      // 33554432 el
  unsigned short* kvb    = ws16 + 67108864;      // 67108864 el
  unsigned short* afb    = ws16 + 134217728;     // 33554432 el
  unsigned short* mdiff  = ws16 + 167772160;     // 16777216 el
  unsigned short* xn2    = ws16 + 184549376;     // 33554432 el
  unsigned short* Wqt    = ws16 + 218103808;     // 65536
  unsigned short* Wkvt   = ws16 + 218169344;     // 131072
  unsigned short* Wprojt = ws16 + 218300416;     // 65536
  unsigned short* Wmpt   = ws16 + 218365952;     // 16384
  unsigned short* Wfc1t  = ws16 + 218382336;     // 262144 (ends 218644480)
  unsigned short* h1     = ws16;                 // 134217728 el
  unsigned short* h2     = ws16 + 134217728;     // 134217728 el
  unsigned short* Wfc2t  = ws16;                 // 262144 el (prepped after conv)

  k_wt<<<dim3(256, 1), 256, 0, stream>>>(Wq,    Wqt,    256, 256);
  k_wt<<<dim3(256, 2), 256, 0, stream>>>(Wkv,   Wkvt,   256, 512);
  k_wt<<<dim3(256, 1), 256, 0, stream>>>(Wproj, Wprojt, 256, 256);
  k_wt<<<dim3(128, 1), 256, 0, stream>>>(Wmp,   Wmpt,   128, 128);
  k_wt<<<dim3(256, 4), 256, 0, stream>>>(Wfc1,  Wfc1t,  256, 1024);
  k_ln1<<<dim3(NTOK/4), 256, 0, stream>>>(x, g1, b1, xnormb);

  k_gemm<0><<<dim3(1024, 2), 256, 0, stream>>>(xnormb, Wqt,  bq,  nullptr, nullptr, qb,  256, 256);
  k_gemm<0><<<dim3(1024, 4), 256, 0, stream>>>(xnormb, Wkvt, bkv, nullptr, nullptr, kvb, 256, 512);
  k_attn2<<<dim3(2048), 512, 0, stream>>>(qb, kvb, cor, Wce, bce, afb, mdiff);
  k_gemm<1><<<dim3(1024, 2), 256, 0, stream>>>(afb, Wprojt, bproj, xnormb, xout, nullptr, 256, 256);
  k_gemm<2><<<dim3(1024, 1), 256, 0, stream>>>(mdiff, Wmpt, bmp, nullptr, mout, nullptr, 128, 128);
  k_ln2<<<dim3(NTOK/4), 256, 0, stream>>>(xout, g2, b2, xn2);
  k_gemm<0><<<dim3(1024, 8), 256, 0, stream>>>(xn2, Wfc1t, bfc1, nullptr, nullptr, h1, 256, 1024);
  k_conv<<<dim3(NTOK), 256, 0, stream>>>(h1, Wdw, bdw, h2);
  k_wt<<<dim3(1024, 1), 256, 0, stream>>>(Wfc2, Wfc2t, 1024, 256);
  k_gemm<3><<<dim3(1024, 2), 256, 0, stream>>>(h2, Wfc2t, bfc2, nullptr, xout, nullptr, 1024, 256);
}